// Round 8
// baseline (161.000 us; speedup 1.0000x reference)
//
#include <hip/hip_runtime.h>
#include <hip/hip_fp16.h>

#define CIN   32
#define COUT  64
#define TT    8
#define HH    56
#define WW    56
#define KK    27
#define SP    (TT * HH * WW)   // 25088
#define NB    2
#define NBLK  784              // (NB*SP)/64
#define KSPLIT 14              // waves 0-3: taps [0,14); waves 4-7: taps [14,27)

typedef __attribute__((ext_vector_type(8))) _Float16 half8;
typedef __attribute__((ext_vector_type(4))) float    f32x4;

// d_ws layout
#define WF_OFF   0                    // weight A-frags (16x16x32): 110,592 B
#define XTH_OFF  (128 << 10)          // xTh fp16 channel-last: 3,211,264 B

// prep: blocks [0,784): x [N][C][SP] fp32 -> xTh [N][SP][C] fp16
//       blocks [784,811): weight -> 16x16x32 A-fragments
//       wf[k][ct][lane][j] = w[co = ct*16 + (lane&15)][c = (lane>>4)*8 + j][k]
__global__ __launch_bounds__(256) void prep_kernel(const float* __restrict__ x,
                                                   const float* __restrict__ w,
                                                   __half* __restrict__ xTh,
                                                   __half* __restrict__ wf) {
    const int b = blockIdx.x;
    const int t = threadIdx.x;
    if (b < NBLK) {
        __shared__ float sm[CIN][65];
        const int s0 = b * 64, n = s0 / SP, sp0 = s0 % SP;
#pragma unroll
        for (int it = 0; it < 8; ++it) {
            const int idx = it * 256 + t, c = idx >> 6, l = idx & 63;
            sm[c][l] = x[((size_t)n * CIN + c) * SP + sp0 + l];
        }
        __syncthreads();
#pragma unroll
        for (int it = 0; it < 4; ++it) {
            const int idx = it * 256 + t, l = idx >> 4, cp = idx & 15;
            ((__half2*)xTh)[((size_t)n * SP + sp0 + l) * (CIN / 2) + cp] =
                __floats2half2_rn(sm[2 * cp][l], sm[2 * cp + 1][l]);
        }
    } else {
        const int k = b - NBLK;        // 2048 elements: [ct(4)][lane(64)][j(8)]
#pragma unroll
        for (int it = 0; it < 8; ++it) {
            const int idx  = it * 256 + t;
            const int j    = idx & 7;
            const int lane = (idx >> 3) & 63;
            const int ct   = (idx >> 9) & 3;
            const int co   = ct * 16 + (lane & 15);
            const int c    = (lane >> 4) * 8 + j;
            wf[(((size_t)k * 4 + ct) * 64 + lane) * 8 + j] =
                __float2half(w[((size_t)co * CIN + c) * KK + k]);
        }
    }
}

// 512-thread blocks: 8 waves = 4 position-tiles x 2 tap-halves.
// Each wave: 16 positions x full Cout, B-fragment built in registers (no LDS
// in the main loop, no barriers until the final combine).
__global__ __launch_bounds__(512, 6) void dconv3d_kernel(const __half* __restrict__ xTh,
                                                         const float* __restrict__ off,
                                                         const __half* __restrict__ wf,
                                                         const float* __restrict__ bias,
                                                         float* __restrict__ out) {
    __shared__ float lds[16][4][64];   // [acc reg][pos-tile wave][lane] - 16 KB

    const int t    = threadIdx.x;
    const int lane = t & 63;
    const int wv   = t >> 6;           // 0..7
    const int wpos = wv & 3;           // position-tile (16 positions each)
    const int half = wv >> 2;          // 0: taps [0,14)+bias, 1: taps [14,27)
    const int posq = lane & 15;
    const int cg   = lane >> 4;        // channel quad: channels cg*8..+7

    // XCD-aware swizzle (bijective on 784; 392*64 == SP so no batch crossing)
    const int sb  = (blockIdx.x & 7) * 98 + (blockIdx.x >> 3);
    const int s0  = sb * 64;
    const int n   = s0 / SP;
    const int spb = s0 % SP;

    const int sp = spb + wpos * 16 + posq;
    const int to = sp / (HH * WW);
    const int hw = sp % (HH * WW);
    const int ho = hw / WW;
    const int wo = hw % WW;

    // bias rides in the MFMA C operand (half 0 only)
    f32x4 acc[4];
#pragma unroll
    for (int ct = 0; ct < 4; ++ct)
#pragma unroll
        for (int r = 0; r < 4; ++r)
            acc[ct][r] = half ? 0.f : bias[ct * 16 + cg * 4 + r];

    const __half* xn   = xTh + (size_t)n * SP * CIN;
    const float*  offn = off + (size_t)n * (3 * KK) * SP + sp;

    auto tap = [&](int k) {
        const int kt  = k / 9;
        const int khh = (k / 3) % 3;
        const int kww = k % 3;

        const float pt_ = (float)(to - 1 + kt)  + offn[(k * 3 + 0) * SP];
        const float ph_ = (float)(ho - 1 + khh) + offn[(k * 3 + 1) * SP];
        const float pw_ = (float)(wo - 1 + kww) + offn[(k * 3 + 2) * SP];

        const float ft = floorf(pt_), fh = floorf(ph_), fw = floorf(pw_);
        const float lt = pt_ - ft, lh = ph_ - fh, lw = pw_ - fw;
        const int t0 = (int)ft, h0 = (int)fh, w0 = (int)fw;
        const int t1 = t0 + 1, h1 = h0 + 1, w1 = w0 + 1;

        float awt[2], awh[2], aww[2];
        int   it2[2], ih2[2], iw2[2];
        awt[0] = (t0 >= 0 && t0 < TT) ? (1.f - lt) : 0.f;
        awt[1] = (t1 >= 0 && t1 < TT) ? lt : 0.f;
        it2[0] = min(max(t0, 0), TT - 1);  it2[1] = min(max(t1, 0), TT - 1);
        awh[0] = (h0 >= 0 && h0 < HH) ? (1.f - lh) : 0.f;
        awh[1] = (h1 >= 0 && h1 < HH) ? lh : 0.f;
        ih2[0] = min(max(h0, 0), HH - 1);  ih2[1] = min(max(h1, 0), HH - 1);
        aww[0] = (w0 >= 0 && w0 < WW) ? (1.f - lw) : 0.f;
        aww[1] = (w1 >= 0 && w1 < WW) ? lw : 0.f;
        iw2[0] = min(max(w0, 0), WW - 1);  iw2[1] = min(max(w1, 0), WW - 1);

        int   a[8];
        float cw[8];
#pragma unroll
        for (int ci = 0; ci < 8; ++ci) {
            const int i0 = ci >> 2, i1 = (ci >> 1) & 1, i2 = ci & 1;
            a[ci]  = (it2[i0] * HH + ih2[i1]) * WW + iw2[i2];
            cw[ci] = awt[i0] * awh[i1] * aww[i2];
        }

        // interp -> B-fragment (channels cg*8..+7 of posq); 4 lanes of a
        // position cover one 64 B xTh line per corner (coalesced)
        float4 g[8];
#pragma unroll
        for (int ci = 0; ci < 8; ++ci)
            g[ci] = *(const float4*)(xn + (size_t)a[ci] * CIN + cg * 8);

        __half2 vacc[4];
#pragma unroll
        for (int j = 0; j < 4; ++j) vacc[j] = __floats2half2_rn(0.f, 0.f);
#pragma unroll
        for (int ci = 0; ci < 8; ++ci) {
            const __half2* uh = (const __half2*)&g[ci];
            const __half2 cw2 = __float2half2_rn(cw[ci]);
            vacc[0] = __hfma2(cw2, uh[0], vacc[0]);
            vacc[1] = __hfma2(cw2, uh[1], vacc[1]);
            vacc[2] = __hfma2(cw2, uh[2], vacc[2]);
            vacc[3] = __hfma2(cw2, uh[3], vacc[3]);
        }
        const half8 bfrag = *(const half8*)vacc;

#pragma unroll
        for (int ct = 0; ct < 4; ++ct) {
            const half8 af = *(const half8*)(wf + (((size_t)k * 4 + ct) * 64 + lane) * 8);
            acc[ct] = __builtin_amdgcn_mfma_f32_16x16x32_f16(af, bfrag, acc[ct], 0, 0, 0);
        }
    };

    if (half == 0) {
#pragma unroll 2
        for (int k = 0; k < KSPLIT; ++k) tap(k);
    } else {
#pragma unroll 2
        for (int k = KSPLIT; k < KK; ++k) tap(k);
    }

    // combine halves through LDS (lane-contiguous layout -> conflict-free)
    if (half == 1) {
#pragma unroll
        for (int ct = 0; ct < 4; ++ct)
#pragma unroll
            for (int r = 0; r < 4; ++r) lds[ct * 4 + r][wpos][lane] = acc[ct][r];
    }
    __syncthreads();
    if (half == 0) {
        // C/D map (16x16): col=lane&15 (pos), row=(lane>>4)*4+reg (co)
#pragma unroll
        for (int ct = 0; ct < 4; ++ct)
#pragma unroll
            for (int r = 0; r < 4; ++r) {
                const int co = ct * 16 + cg * 4 + r;
                out[((size_t)n * COUT + co) * SP + spb + wpos * 16 + posq] =
                    acc[ct][r] + lds[ct * 4 + r][wpos][lane];
            }
    }
}

extern "C" void kernel_launch(void* const* d_in, const int* in_sizes, int n_in,
                              void* d_out, int out_size, void* d_ws, size_t ws_size,
                              hipStream_t stream) {
    const float* x    = (const float*)d_in[0];
    const float* off  = (const float*)d_in[1];
    const float* w    = (const float*)d_in[2];
    const float* bias = (const float*)d_in[3];
    float* out        = (float*)d_out;

    __half* wf  = (__half*)((char*)d_ws + WF_OFF);
    __half* xTh = (__half*)((char*)d_ws + XTH_OFF);

    prep_kernel<<<NBLK + KK, 256, 0, stream>>>(x, w, xTh, wf);
    dconv3d_kernel<<<NBLK, 512, 0, stream>>>(xTh, off, wf, bias, out);
}

// Round 9
// 138.583 us; speedup vs baseline: 1.1618x; 1.1618x over previous
//
#include <hip/hip_runtime.h>
#include <hip/hip_fp16.h>

#define CIN   32
#define COUT  64
#define TT    8
#define HH    56
#define WW    56
#define KK    27
#define SP    (TT * HH * WW)   // 25088
#define NB    2
#define NBLK  784              // (NB*SP)/64
#define KSPLIT 14              // waves 0-3: taps [0,14)+bias; waves 4-7: [14,27)

typedef __attribute__((ext_vector_type(8))) _Float16 half8;
typedef __attribute__((ext_vector_type(4))) float    f32x4;

// d_ws layout
#define WF_OFF   0                    // weight A-frags (16x16x32): 110,592 B
#define XTH_OFF  (128 << 10)          // xTh fp16 channel-last: 3,211,264 B

// prep: blocks [0,784): x [N][C][SP] fp32 -> xTh [N][SP][C] fp16
//       blocks [784,811): weight -> 16x16x32 A-fragments
//       wf[k][ct][lane][j] = w[co = ct*16 + (lane&15)][c = (lane>>4)*8 + j][k]
__global__ __launch_bounds__(256) void prep_kernel(const float* __restrict__ x,
                                                   const float* __restrict__ w,
                                                   __half* __restrict__ xTh,
                                                   __half* __restrict__ wf) {
    const int b = blockIdx.x;
    const int t = threadIdx.x;
    if (b < NBLK) {
        __shared__ float sm[CIN][65];
        const int s0 = b * 64, n = s0 / SP, sp0 = s0 % SP;
#pragma unroll
        for (int it = 0; it < 8; ++it) {
            const int idx = it * 256 + t, c = idx >> 6, l = idx & 63;
            sm[c][l] = x[((size_t)n * CIN + c) * SP + sp0 + l];
        }
        __syncthreads();
#pragma unroll
        for (int it = 0; it < 4; ++it) {
            const int idx = it * 256 + t, l = idx >> 4, cp = idx & 15;
            ((__half2*)xTh)[((size_t)n * SP + sp0 + l) * (CIN / 2) + cp] =
                __floats2half2_rn(sm[2 * cp][l], sm[2 * cp + 1][l]);
        }
    } else {
        const int k = b - NBLK;        // 2048 elements: [ct(4)][lane(64)][j(8)]
#pragma unroll
        for (int it = 0; it < 8; ++it) {
            const int idx  = it * 256 + t;
            const int j    = idx & 7;
            const int lane = (idx >> 3) & 63;
            const int ct   = (idx >> 9) & 3;
            const int co   = ct * 16 + (lane & 15);
            const int c    = (lane >> 4) * 8 + j;
            wf[(((size_t)k * 4 + ct) * 64 + lane) * 8 + j] =
                __float2half(w[((size_t)co * CIN + c) * KK + k]);
        }
    }
}

// 512-thread blocks: 8 waves = 4 position-tiles x 2 tap-halves.
// Interp persona: pos = lane>>2, cg = lane&3 -> each lane-QUAD reads one
// aligned 64 B xTh line per corner (TA merges 4 addr/cyc within a quad).
// Repack to MFMA B-layout via 4x ds_bpermute (intra-wave, no LDS storage).
__global__ __launch_bounds__(512, 6) void dconv3d_kernel(const __half* __restrict__ xTh,
                                                         const float* __restrict__ off,
                                                         const __half* __restrict__ wf,
                                                         const float* __restrict__ bias,
                                                         float* __restrict__ out) {
    __shared__ float lds[16][4][64];   // final half-combine only - 16 KB

    const int t    = threadIdx.x;
    const int lane = t & 63;
    const int wv   = t >> 6;           // 0..7
    const int wpos = wv & 3;           // position-tile (16 positions each)
    const int half = wv >> 2;          // 0: taps [0,14)+bias, 1: taps [14,27)

    // interp persona (quad-aligned gathers)
    const int posI = lane >> 2;        // 0..15
    const int cgI  = lane & 3;         // channels cgI*8 .. +7
    // gemm persona (MFMA B/C fixed layout)
    const int jg   = lane >> 4;        // B k-group / C row-group

    // bpermute source lane for B-frag repack: src = 4*(lane&15) + (lane>>4)
    const int bp_addr = (((lane & 15) << 2) | jg) << 2;  // byte index = srcLane*4

    // XCD-aware swizzle (bijective on 784; 392*64 == SP so no batch crossing)
    const int sb  = (blockIdx.x & 7) * 98 + (blockIdx.x >> 3);
    const int s0  = sb * 64;
    const int n   = s0 / SP;
    const int spb = s0 % SP;

    const int sp = spb + wpos * 16 + posI;
    const int to = sp / (HH * WW);
    const int hw = sp % (HH * WW);
    const int ho = hw / WW;
    const int wo = hw % WW;

    // bias rides in the MFMA C operand (half 0 only)
    f32x4 acc[4];
#pragma unroll
    for (int ct = 0; ct < 4; ++ct)
#pragma unroll
        for (int r = 0; r < 4; ++r)
            acc[ct][r] = half ? 0.f : bias[ct * 16 + jg * 4 + r];

    const __half* xn   = xTh + (size_t)n * SP * CIN;
    const float*  offn = off + (size_t)n * (3 * KK) * SP + sp;

    auto tap = [&](int k) {
        const int kt  = k / 9;
        const int khh = (k / 3) % 3;
        const int kww = k % 3;

        const float pt_ = (float)(to - 1 + kt)  + offn[(k * 3 + 0) * SP];
        const float ph_ = (float)(ho - 1 + khh) + offn[(k * 3 + 1) * SP];
        const float pw_ = (float)(wo - 1 + kww) + offn[(k * 3 + 2) * SP];

        const float ft = floorf(pt_), fh = floorf(ph_), fw = floorf(pw_);
        const float lt = pt_ - ft, lh = ph_ - fh, lw = pw_ - fw;
        const int t0 = (int)ft, h0 = (int)fh, w0 = (int)fw;
        const int t1 = t0 + 1, h1 = h0 + 1, w1 = w0 + 1;

        float awt[2], awh[2], aww[2];
        int   it2[2], ih2[2], iw2[2];
        awt[0] = (t0 >= 0 && t0 < TT) ? (1.f - lt) : 0.f;
        awt[1] = (t1 >= 0 && t1 < TT) ? lt : 0.f;
        it2[0] = min(max(t0, 0), TT - 1);  it2[1] = min(max(t1, 0), TT - 1);
        awh[0] = (h0 >= 0 && h0 < HH) ? (1.f - lh) : 0.f;
        awh[1] = (h1 >= 0 && h1 < HH) ? lh : 0.f;
        ih2[0] = min(max(h0, 0), HH - 1);  ih2[1] = min(max(h1, 0), HH - 1);
        aww[0] = (w0 >= 0 && w0 < WW) ? (1.f - lw) : 0.f;
        aww[1] = (w1 >= 0 && w1 < WW) ? lw : 0.f;
        iw2[0] = min(max(w0, 0), WW - 1);  iw2[1] = min(max(w1, 0), WW - 1);

        int   a[8];
        float cw[8];
#pragma unroll
        for (int ci = 0; ci < 8; ++ci) {
            const int i0 = ci >> 2, i1 = (ci >> 1) & 1, i2 = ci & 1;
            a[ci]  = (it2[i0] * HH + ih2[i1]) * WW + iw2[i2];
            cw[ci] = awt[i0] * awh[i1] * aww[i2];
        }

        // gathers: quad-aligned, one 64 B line per corner per quad
        float4 g[8];
#pragma unroll
        for (int ci = 0; ci < 8; ++ci)
            g[ci] = *(const float4*)(xn + (size_t)a[ci] * CIN + cgI * 8);

        __half2 vacc[4];
#pragma unroll
        for (int j = 0; j < 4; ++j) vacc[j] = __floats2half2_rn(0.f, 0.f);
#pragma unroll
        for (int ci = 0; ci < 8; ++ci) {
            const __half2* uh = (const __half2*)&g[ci];
            const __half2 cw2 = __float2half2_rn(cw[ci]);
            vacc[0] = __hfma2(cw2, uh[0], vacc[0]);
            vacc[1] = __hfma2(cw2, uh[1], vacc[1]);
            vacc[2] = __hfma2(cw2, uh[2], vacc[2]);
            vacc[3] = __hfma2(cw2, uh[3], vacc[3]);
        }

        // repack (pos=lane>>2, ch=lane&3) -> B-frag (pos=lane&15, ch-grp=lane>>4)
        union { __half2 h2[4]; int i[4]; half8 h8; } u, v;
#pragma unroll
        for (int d = 0; d < 4; ++d) u.h2[d] = vacc[d];
#pragma unroll
        for (int d = 0; d < 4; ++d)
            v.i[d] = __builtin_amdgcn_ds_bpermute(bp_addr, u.i[d]);
        const half8 bfrag = v.h8;

#pragma unroll
        for (int ct = 0; ct < 4; ++ct) {
            const half8 af = *(const half8*)(wf + (((size_t)k * 4 + ct) * 64 + lane) * 8);
            acc[ct] = __builtin_amdgcn_mfma_f32_16x16x32_f16(af, bfrag, acc[ct], 0, 0, 0);
        }
    };

    if (half == 0) {
#pragma unroll 2
        for (int k = 0; k < KSPLIT; ++k) tap(k);
    } else {
#pragma unroll 2
        for (int k = KSPLIT; k < KK; ++k) tap(k);
    }

    // combine halves through LDS (lane-contiguous -> conflict-free)
    if (half == 1) {
#pragma unroll
        for (int ct = 0; ct < 4; ++ct)
#pragma unroll
            for (int r = 0; r < 4; ++r) lds[ct * 4 + r][wpos][lane] = acc[ct][r];
    }
    __syncthreads();
    if (half == 0) {
        // C/D map (16x16): col=lane&15 (pos), row=(lane>>4)*4+reg (co)
#pragma unroll
        for (int ct = 0; ct < 4; ++ct)
#pragma unroll
            for (int r = 0; r < 4; ++r) {
                const int co = ct * 16 + jg * 4 + r;
                out[((size_t)n * COUT + co) * SP + spb + wpos * 16 + (lane & 15)] =
                    acc[ct][r] + lds[ct * 4 + r][wpos][lane];
            }
    }
}

extern "C" void kernel_launch(void* const* d_in, const int* in_sizes, int n_in,
                              void* d_out, int out_size, void* d_ws, size_t ws_size,
                              hipStream_t stream) {
    const float* x    = (const float*)d_in[0];
    const float* off  = (const float*)d_in[1];
    const float* w    = (const float*)d_in[2];
    const float* bias = (const float*)d_in[3];
    float* out        = (float*)d_out;

    __half* wf  = (__half*)((char*)d_ws + WF_OFF);
    __half* xTh = (__half*)((char*)d_ws + XTH_OFF);

    prep_kernel<<<NBLK + KK, 256, 0, stream>>>(x, w, xTh, wf);
    dconv3d_kernel<<<NBLK, 512, 0, stream>>>(xTh, off, wf, bias, out);
}

// Round 10
// 124.421 us; speedup vs baseline: 1.2940x; 1.1138x over previous
//
#include <hip/hip_runtime.h>
#include <hip/hip_fp16.h>

#define CIN   32
#define COUT  64
#define TT    8
#define HH    56
#define WW    56
#define KK    27
#define SP    (TT * HH * WW)   // 25088
#define NB    2
#define NBLK  784              // (NB*SP)/64
#define KSPLIT 14              // waves 0-3: taps [0,14)+bias; waves 4-7: [14,27)

typedef __attribute__((ext_vector_type(8))) _Float16 half8;
typedef __attribute__((ext_vector_type(4))) float    f32x4;

// d_ws layout
#define WF_OFF   0                    // weight A-frags (16x16x32): 110,592 B
#define XTH_OFF  (128 << 10)          // xTh fp16 channel-last: 3,211,264 B

// prep: blocks [0,784): x [N][C][SP] fp32 -> xTh [N][SP][C] fp16
//       blocks [784,811): weight -> 16x16x32 A-fragments
//       wf[k][ct][lane][j] = w[co = ct*16 + (lane&15)][c = (lane>>4)*8 + j][k]
__global__ __launch_bounds__(256) void prep_kernel(const float* __restrict__ x,
                                                   const float* __restrict__ w,
                                                   __half* __restrict__ xTh,
                                                   __half* __restrict__ wf) {
    const int b = blockIdx.x;
    const int t = threadIdx.x;
    if (b < NBLK) {
        __shared__ float sm[CIN][65];
        const int s0 = b * 64, n = s0 / SP, sp0 = s0 % SP;
#pragma unroll
        for (int it = 0; it < 8; ++it) {
            const int idx = it * 256 + t, c = idx >> 6, l = idx & 63;
            sm[c][l] = x[((size_t)n * CIN + c) * SP + sp0 + l];
        }
        __syncthreads();
#pragma unroll
        for (int it = 0; it < 4; ++it) {
            const int idx = it * 256 + t, l = idx >> 4, cp = idx & 15;
            ((__half2*)xTh)[((size_t)n * SP + sp0 + l) * (CIN / 2) + cp] =
                __floats2half2_rn(sm[2 * cp][l], sm[2 * cp + 1][l]);
        }
    } else {
        const int k = b - NBLK;        // 2048 elements: [ct(4)][lane(64)][j(8)]
#pragma unroll
        for (int it = 0; it < 8; ++it) {
            const int idx  = it * 256 + t;
            const int j    = idx & 7;
            const int lane = (idx >> 3) & 63;
            const int ct   = (idx >> 9) & 3;
            const int co   = ct * 16 + (lane & 15);
            const int c    = (lane >> 4) * 8 + j;
            wf[(((size_t)k * 4 + ct) * 64 + lane) * 8 + j] =
                __float2half(w[((size_t)co * CIN + c) * KK + k]);
        }
    }
}

// 512-thread blocks: 8 waves = 4 position-tiles x 2 tap-halves.
// Offsets LDS-staged once per block (off the TA path); gathers quad-aligned;
// B-frag repack via ds_bpermute; final half-combine reuses the offset LDS.
__global__ __launch_bounds__(512, 6) void dconv3d_kernel(const __half* __restrict__ xTh,
                                                         const float* __restrict__ off,
                                                         const __half* __restrict__ wf,
                                                         const float* __restrict__ bias,
                                                         float* __restrict__ out) {
    // 20.7 KB: offsets [81][64] during main loop; combine [16][4][64] at end
    __shared__ __align__(16) char smem[81 * 64 * 4];
    float (*offs)[64] = reinterpret_cast<float(*)[64]>(smem);
    float (*cmb)[4][64] = reinterpret_cast<float(*)[4][64]>(smem);

    const int t    = threadIdx.x;
    const int lane = t & 63;
    const int wv   = t >> 6;           // 0..7
    const int wpos = wv & 3;           // position-tile (16 positions each)
    const int half = wv >> 2;          // 0: taps [0,14)+bias, 1: taps [14,27)

    // interp persona (quad-aligned gathers)
    const int posI = lane >> 2;        // 0..15
    const int cgI  = lane & 3;         // channels cgI*8 .. +7
    // gemm persona (MFMA B/C fixed layout)
    const int jg   = lane >> 4;        // B k-group / C row-group

    // bpermute source lane: src = 4*(lane&15) + (lane>>4); byte addr = src*4
    const int bp_addr = (((lane & 15) << 2) | jg) << 2;

    // XCD-aware swizzle (bijective on 784; 392*64 == SP so no batch crossing)
    const int sb  = (blockIdx.x & 7) * 98 + (blockIdx.x >> 3);
    const int s0  = sb * 64;
    const int n   = s0 / SP;
    const int spb = s0 % SP;

    // ---- stage offsets: off[n][row][spb..spb+64) -> offs[row][0..64), row=k*3+d
    {
        const float* offbase = off + ((size_t)n * (3 * KK)) * SP + spb;
        // 81 rows x 16 float4 = 1296 float4 elements
        for (int i = t; i < 81 * 16; i += 512) {
            const int row = i >> 4, q = i & 15;
            *(float4*)&offs[row][q * 4] = *(const float4*)(offbase + (size_t)row * SP + q * 4);
        }
    }
    __syncthreads();

    const int sp = spb + wpos * 16 + posI;
    const int to = sp / (HH * WW);
    const int hw = sp % (HH * WW);
    const int ho = hw / WW;
    const int wo = hw % WW;
    const int pl = wpos * 16 + posI;   // local position index 0..63

    // bias rides in the MFMA C operand (half 0 only)
    f32x4 acc[4];
#pragma unroll
    for (int ct = 0; ct < 4; ++ct)
#pragma unroll
        for (int r = 0; r < 4; ++r)
            acc[ct][r] = half ? 0.f : bias[ct * 16 + jg * 4 + r];

    const __half* xn = xTh + (size_t)n * SP * CIN;

    auto tap = [&](int k) {
        const int kt  = k / 9;
        const int khh = (k / 3) % 3;
        const int kww = k % 3;

        const float pt_ = (float)(to - 1 + kt)  + offs[k * 3 + 0][pl];
        const float ph_ = (float)(ho - 1 + khh) + offs[k * 3 + 1][pl];
        const float pw_ = (float)(wo - 1 + kww) + offs[k * 3 + 2][pl];

        const float ft = floorf(pt_), fh = floorf(ph_), fw = floorf(pw_);
        const float lt = pt_ - ft, lh = ph_ - fh, lw = pw_ - fw;
        const int t0 = (int)ft, h0 = (int)fh, w0 = (int)fw;
        const int t1 = t0 + 1, h1 = h0 + 1, w1 = w0 + 1;

        float awt[2], awh[2], aww[2];
        int   it2[2], ih2[2], iw2[2];
        awt[0] = (t0 >= 0 && t0 < TT) ? (1.f - lt) : 0.f;
        awt[1] = (t1 >= 0 && t1 < TT) ? lt : 0.f;
        it2[0] = min(max(t0, 0), TT - 1);  it2[1] = min(max(t1, 0), TT - 1);
        awh[0] = (h0 >= 0 && h0 < HH) ? (1.f - lh) : 0.f;
        awh[1] = (h1 >= 0 && h1 < HH) ? lh : 0.f;
        ih2[0] = min(max(h0, 0), HH - 1);  ih2[1] = min(max(h1, 0), HH - 1);
        aww[0] = (w0 >= 0 && w0 < WW) ? (1.f - lw) : 0.f;
        aww[1] = (w1 >= 0 && w1 < WW) ? lw : 0.f;
        iw2[0] = min(max(w0, 0), WW - 1);  iw2[1] = min(max(w1, 0), WW - 1);

        int   a[8];
        float cw[8];
#pragma unroll
        for (int ci = 0; ci < 8; ++ci) {
            const int i0 = ci >> 2, i1 = (ci >> 1) & 1, i2 = ci & 1;
            a[ci]  = (it2[i0] * HH + ih2[i1]) * WW + iw2[i2];
            cw[ci] = awt[i0] * awh[i1] * aww[i2];
        }

        // gathers: quad-aligned, one 64 B xTh line per corner per quad
        float4 g[8];
#pragma unroll
        for (int ci = 0; ci < 8; ++ci)
            g[ci] = *(const float4*)(xn + (size_t)a[ci] * CIN + cgI * 8);

        __half2 vacc[4];
#pragma unroll
        for (int j = 0; j < 4; ++j) vacc[j] = __floats2half2_rn(0.f, 0.f);
#pragma unroll
        for (int ci = 0; ci < 8; ++ci) {
            const __half2* uh = (const __half2*)&g[ci];
            const __half2 cw2 = __float2half2_rn(cw[ci]);
            vacc[0] = __hfma2(cw2, uh[0], vacc[0]);
            vacc[1] = __hfma2(cw2, uh[1], vacc[1]);
            vacc[2] = __hfma2(cw2, uh[2], vacc[2]);
            vacc[3] = __hfma2(cw2, uh[3], vacc[3]);
        }

        // repack (pos=lane>>2, ch=lane&3) -> B-frag (pos=lane&15, ch-grp=lane>>4)
        union { __half2 h2[4]; int i[4]; half8 h8; } u, v;
#pragma unroll
        for (int d = 0; d < 4; ++d) u.h2[d] = vacc[d];
#pragma unroll
        for (int d = 0; d < 4; ++d)
            v.i[d] = __builtin_amdgcn_ds_bpermute(bp_addr, u.i[d]);
        const half8 bfrag = v.h8;

#pragma unroll
        for (int ct = 0; ct < 4; ++ct) {
            const half8 af = *(const half8*)(wf + (((size_t)k * 4 + ct) * 64 + lane) * 8);
            acc[ct] = __builtin_amdgcn_mfma_f32_16x16x32_f16(af, bfrag, acc[ct], 0, 0, 0);
        }
    };

    if (half == 0) {
#pragma unroll 2
        for (int k = 0; k < KSPLIT; ++k) tap(k);
    } else {
#pragma unroll 2
        for (int k = KSPLIT; k < KK; ++k) tap(k);
    }

    // LDS reuse boundary: all offset reads must be done before combine writes
    __syncthreads();
    if (half == 1) {
#pragma unroll
        for (int ct = 0; ct < 4; ++ct)
#pragma unroll
            for (int r = 0; r < 4; ++r) cmb[ct * 4 + r][wpos][lane] = acc[ct][r];
    }
    __syncthreads();
    if (half == 0) {
        // C/D map (16x16): col=lane&15 (pos), row=(lane>>4)*4+reg (co)
#pragma unroll
        for (int ct = 0; ct < 4; ++ct)
#pragma unroll
            for (int r = 0; r < 4; ++r) {
                const int co = ct * 16 + jg * 4 + r;
                out[((size_t)n * COUT + co) * SP + spb + wpos * 16 + (lane & 15)] =
                    acc[ct][r] + cmb[ct * 4 + r][wpos][lane];
            }
    }
}

extern "C" void kernel_launch(void* const* d_in, const int* in_sizes, int n_in,
                              void* d_out, int out_size, void* d_ws, size_t ws_size,
                              hipStream_t stream) {
    const float* x    = (const float*)d_in[0];
    const float* off  = (const float*)d_in[1];
    const float* w    = (const float*)d_in[2];
    const float* bias = (const float*)d_in[3];
    float* out        = (float*)d_out;

    __half* wf  = (__half*)((char*)d_ws + WF_OFF);
    __half* xTh = (__half*)((char*)d_ws + XTH_OFF);

    prep_kernel<<<NBLK + KK, 256, 0, stream>>>(x, w, xTh, wf);
    dconv3d_kernel<<<NBLK, 512, 0, stream>>>(xTh, off, wf, bias, out);
}